// Round 3
// baseline (253.164 us; speedup 1.0000x reference)
//
#include <hip/hip_runtime.h>

#define PLANES 384
#define K 11
#define TS 88            // row stride in floats; rows in a wave differ by 4 -> skew (row&12) gives distinct bank-quads
#define ROWS 74          // 5 pad + 64 + 5 pad

// One block = one (n,c) plane of 64x64. 256 threads, each computes a 4x4 output tile.
// LDS layout: tile[row*TS + (row&12) + 8 + gx] = x[plane][row-5][gx]; halo zeroed (padding).
// Window reads may spill <=4 floats past a row's stride into the next row's always-zero
// left-pad region (data starts at index skew+8 >= 8); +16 array pad covers the last row.
//
// Window ds_read_b128 quads are gated by the union column mask of the kernel rows
// active this iteration: ~85% of quads feed no nonzero tap (4 points, narrow L1 hats)
// and skipping them removes both their issue slots and their bank-conflict cycles
// (round-1 evidence: conflicts 14.9M -> 2.06M with gating; round-2 evidence: skv
// broadcast reads contribute ~0 conflicts in either b128 or b32 form).
__global__ __launch_bounds__(256) void smpconv_kernel(
    const float* __restrict__ x,
    const float* __restrict__ wcoord,   // (1,4,2)
    const float* __restrict__ radius,   // (1,4,1,1)
    const float* __restrict__ wts,      // (1,384,4)
    float* __restrict__ out)
{
    __shared__ __align__(16) float tile[ROWS * TS + 16];   // 26176 B
    __shared__ __align__(16) float skv[12 * 12];           // 11 kernel rows, stride 12
    __shared__ int s_rcmask[K];                            // per-kernel-row column bitmask

    const int tid = threadIdx.x;
    const int bid = blockIdx.x;          // n*384 + c
    const int c   = bid % PLANES;

    // ---- phase 0: zero LDS tile (halo = conv zero padding) ----
    #pragma unroll
    for (int z = 0; z < 7; ++z) {
        int e = z * 256 + tid;
        if (e < (ROWS * TS + 16) / 4) {
            float4 zz; zz.x = zz.y = zz.z = zz.w = 0.f;
            *(float4*)&tile[e * 4] = zz;
        }
    }
    if (tid < K) s_rcmask[tid] = 0;
    __syncthreads();

    // ---- phase 1: stage input plane (skewed) + generate this channel's 11x11 kernel ----
    const float* xp = x + (size_t)bid * 4096;
    #pragma unroll
    for (int it = 0; it < 4; ++it) {
        int e = it * 256 + tid;              // float4 index 0..1023
        float4 v = ((const float4*)xp)[e];
        int gy = e >> 4;                     // 16 float4 per 64-wide row
        int gx = (e & 15) << 2;
        int row = gy + 5;
        *(float4*)&tile[row * TS + (row & 12) + 8 + gx] = v;
    }
    if (tid < K * K) {
        // kf[c,i,j] = sum_p w[c,p] * relu(1 - (|wc0 - lin[j]| + |wc1 - lin[10-i]|)/r[p])
        int i = tid / K;
        int j = tid - i * K;
        float la = -1.f + 0.2f * (float)j;
        float lb = -1.f + 0.2f * (float)(10 - i);
        float a = 0.f;
        #pragma unroll
        for (int p = 0; p < 4; ++p) {
            float ir = 1.f / radius[p];
            float t = 1.f - (fabsf(wcoord[2*p] - la) + fabsf(wcoord[2*p+1] - lb)) * ir;
            t = fmaxf(t, 0.f);
            a = fmaf(wts[c*4 + p], t, a);
        }
        skv[i * 12 + j] = a;
        if (a != 0.f) atomicOr(&s_rcmask[i], 1 << j);
    }
    __syncthreads();

    // ---- wave-uniform sparsity masks in SGPRs (scalar branches only; no conditional loads) ----
    int rc[K];
    int rowmask = 0;
    #pragma unroll
    for (int i = 0; i < K; ++i) {
        rc[i] = __builtin_amdgcn_readfirstlane(s_rcmask[i]);
        if (rc[i]) rowmask |= 1 << i;
    }

    const int ty = tid >> 4;     // 0..15 -> output rows 4ty..4ty+3
    const int tx = tid & 15;     // 0..15 -> output cols 4tx..4tx+3

    float acc[4][4] = {};
    float kvs[4][12] = {};       // rotating cache of 4 kernel rows (fully unrolled -> regs)

    const float* colbase = tile + tx * 4;

    #pragma unroll
    for (int rr = 0; rr < 14; ++rr) {      // input rows 4ty+rr-5; kernel row i = rr-o
        // rotate in kernel row rr (UNCONDITIONAL quads when row active -> no cond-defined regs)
        if (rr < K) {
            if ((rowmask >> rr) & 1) {
                const int s = rr & 3;
                float4 k0 = *(const float4*)&skv[rr*12 + 0];
                float4 k1 = *(const float4*)&skv[rr*12 + 4];
                float4 k2 = *(const float4*)&skv[rr*12 + 8];
                kvs[s][0]=k0.x; kvs[s][1]=k0.y; kvs[s][2]=k0.z; kvs[s][3]=k0.w;
                kvs[s][4]=k1.x; kvs[s][5]=k1.y; kvs[s][6]=k1.z; kvs[s][7]=k1.w;
                kvs[s][8]=k2.x; kvs[s][9]=k2.y; kvs[s][10]=k2.z; kvs[s][11]=k2.w;
            }
        }
        // need bit (3-o) <=> kernel row i=rr-o exists and is nonzero
        const int need = ((rowmask << 3) >> rr) & 0xF;
        if (need) {
            // union column mask over the <=4 kernel rows active this iteration
            int um = 0;
            #pragma unroll
            for (int b = 0; b < 4; ++b) {          // bit b of need <-> kernel row rr-3+b
                const int i = rr - 3 + b;
                if (i >= 0 && i < K)
                    if ((need >> b) & 1) um |= rc[i];
            }
            // window-float usage mask: tap j reads w[j+3..j+6]
            const int wm = (um << 3) | (um << 4) | (um << 5) | (um << 6);

            const int row = ty * 4 + rr;
            const float* rp = colbase + row * TS + (row & 12);   // skewed row base
            float w[20];
            #pragma unroll
            for (int q = 0; q < 5; ++q) {
                if ((wm >> (4 * q)) & 0xF) {       // scalar branch: quad feeds an active tap?
                    const float4 qq = *(const float4*)(rp + 4 * q);
                    w[4*q+0] = qq.x; w[4*q+1] = qq.y; w[4*q+2] = qq.z; w[4*q+3] = qq.w;
                }
            }
            #pragma unroll
            for (int o = 0; o < 4; ++o) {
                if (rr - o >= 0 && rr - o < K) {           // compile-time fold
                    if ((need >> (3 - o)) & 1) {
                        const int m = rc[rr - o];          // per-row column mask (SGPR)
                        const int s = (rr - o) & 3;
                        #pragma unroll
                        for (int j = 0; j < K; ++j) {
                            if ((m >> j) & 1) {            // scalar branch gates FMAs only
                                const float kv = kvs[s][j];
                                // plane col = 4tx+xx+j-5 -> window index xx+j+3
                                #pragma unroll
                                for (int xx = 0; xx < 4; ++xx)
                                    acc[o][xx] = fmaf(w[xx + j + 3], kv, acc[o][xx]);
                            }
                        }
                    }
                }
            }
        }
    }

    float* op = out + (size_t)bid * 4096 + (ty * 4) * 64 + tx * 4;
    #pragma unroll
    for (int o = 0; o < 4; ++o) {
        float4 v;
        v.x = acc[o][0]; v.y = acc[o][1]; v.z = acc[o][2]; v.w = acc[o][3];
        *(float4*)(op + o * 64) = v;
    }
}

extern "C" void kernel_launch(void* const* d_in, const int* in_sizes, int n_in,
                              void* d_out, int out_size, void* d_ws, size_t ws_size,
                              hipStream_t stream) {
    const float* x      = (const float*)d_in[0];
    const float* wcoord = (const float*)d_in[1];
    const float* radius = (const float*)d_in[2];
    const float* wts    = (const float*)d_in[3];
    float* out          = (float*)d_out;

    const int nplanes = 16 * PLANES;   // 6144 blocks, one 64x64 plane each
    smpconv_kernel<<<dim3(nplanes), dim3(256), 0, stream>>>(x, wcoord, radius, wts, out);
}

// Round 4
// 212.225 us; speedup vs baseline: 1.1929x; 1.1929x over previous
//
#include <hip/hip_runtime.h>

#define PLANES 384
#define K 11
#define TS 88            // row stride in floats; rows in a wave differ by 2 -> skew (row&12) decorrelates bank-quads
#define ROWS 74          // 5 pad + 64 + 5 pad

// One block = one (n,c) plane of 64x64. 512 threads, each computes a 2x4 output tile.
// Rationale (R0-R3 evidence): kernel is latency-bound (per-SIMD VALU issue ~17%, LDS pipe
// ~60%, HBM 19%, occupancy 43.5% = 3.5 waves/SIMD). Conflict-removal variants (R1/R3) all
// lost more to VGPR/occupancy than they gained. This version keeps the proven round-0
// codegen shape but doubles resident waves: LDS ~27KB -> 4 blocks/CU x 8 waves = 32
// waves/CU (HW cap). Per-thread tile halves (2 rows), so live regs fit 64-VGPR/8-wave.
//
// LDS layout: tile[row*TS + (row&12) + 8 + gx] = x[plane][row-5][gx]; halo zeroed (padding).
// Window reads may spill <=4 floats past a row's stride into the next row's always-zero
// left-pad region (data starts at index skew+8 >= 8); +16 array pad covers the last row.
__global__ __launch_bounds__(512, 8) void smpconv_kernel(
    const float* __restrict__ x,
    const float* __restrict__ wcoord,   // (1,4,2)
    const float* __restrict__ radius,   // (1,4,1,1)
    const float* __restrict__ wts,      // (1,384,4)
    float* __restrict__ out)
{
    __shared__ __align__(16) float tile[ROWS * TS + 16];   // 26176 B
    __shared__ __align__(16) float skv[12 * 12];           // 11 kernel rows, stride 12
    __shared__ int s_rcmask[K];                            // per-kernel-row column bitmask

    const int tid = threadIdx.x;
    const int bid = blockIdx.x;          // n*384 + c
    const int c   = bid % PLANES;

    // ---- phase 0: zero LDS tile (halo = conv zero padding) ----
    #pragma unroll
    for (int z = 0; z < 4; ++z) {
        int e = z * 512 + tid;
        if (e < (ROWS * TS + 16) / 4) {
            float4 zz; zz.x = zz.y = zz.z = zz.w = 0.f;
            *(float4*)&tile[e * 4] = zz;
        }
    }
    if (tid < K) s_rcmask[tid] = 0;
    __syncthreads();

    // ---- phase 1: stage input plane (skewed) + generate this channel's 11x11 kernel ----
    const float* xp = x + (size_t)bid * 4096;
    #pragma unroll
    for (int it = 0; it < 2; ++it) {
        int e = it * 512 + tid;              // float4 index 0..1023
        float4 v = ((const float4*)xp)[e];
        int gy = e >> 4;                     // 16 float4 per 64-wide row
        int gx = (e & 15) << 2;
        int row = gy + 5;
        *(float4*)&tile[row * TS + (row & 12) + 8 + gx] = v;
    }
    if (tid < K * K) {
        // kf[c,i,j] = sum_p w[c,p] * relu(1 - (|wc0 - lin[j]| + |wc1 - lin[10-i]|)/r[p])
        int i = tid / K;
        int j = tid - i * K;
        float la = -1.f + 0.2f * (float)j;
        float lb = -1.f + 0.2f * (float)(10 - i);
        float a = 0.f;
        #pragma unroll
        for (int p = 0; p < 4; ++p) {
            float ir = 1.f / radius[p];
            float t = 1.f - (fabsf(wcoord[2*p] - la) + fabsf(wcoord[2*p+1] - lb)) * ir;
            t = fmaxf(t, 0.f);
            a = fmaf(wts[c*4 + p], t, a);
        }
        skv[i * 12 + j] = a;
        if (a != 0.f) atomicOr(&s_rcmask[i], 1 << j);
    }
    __syncthreads();

    // ---- wave-uniform sparsity masks in SGPRs (scalar branches only; no conditional loads) ----
    int rc[K];
    int rowmask = 0;
    #pragma unroll
    for (int i = 0; i < K; ++i) {
        rc[i] = __builtin_amdgcn_readfirstlane(s_rcmask[i]);
        if (rc[i]) rowmask |= 1 << i;
    }

    const int ty = tid >> 4;     // 0..31 -> output rows 2ty, 2ty+1
    const int tx = tid & 15;     // 0..15 -> output cols 4tx..4tx+3

    float acc[2][4] = {};
    float kvs[2][12] = {};       // rotating cache of 2 kernel rows (fully unrolled -> regs)

    const float* colbase = tile + tx * 4;

    #pragma unroll
    for (int rr = 0; rr < 12; ++rr) {      // input rows 2ty+rr-5; kernel row i = rr-o, o in {0,1}
        // rotate in kernel row rr (UNCONDITIONAL quads when row active -> no cond-defined regs)
        if (rr < K) {
            if ((rowmask >> rr) & 1) {
                const int s = rr & 1;
                float4 k0 = *(const float4*)&skv[rr*12 + 0];
                float4 k1 = *(const float4*)&skv[rr*12 + 4];
                float4 k2 = *(const float4*)&skv[rr*12 + 8];
                kvs[s][0]=k0.x; kvs[s][1]=k0.y; kvs[s][2]=k0.z; kvs[s][3]=k0.w;
                kvs[s][4]=k1.x; kvs[s][5]=k1.y; kvs[s][6]=k1.z; kvs[s][7]=k1.w;
                kvs[s][8]=k2.x; kvs[s][9]=k2.y; kvs[s][10]=k2.z; kvs[s][11]=k2.w;
            }
        }
        // need bit o <=> kernel row i=rr-o exists and is nonzero
        int need = 0;
        if (rr < K && ((rowmask >> rr) & 1))            need |= 1;
        if (rr >= 1 && rr - 1 < K && ((rowmask >> (rr - 1)) & 1)) need |= 2;
        if (need) {
            const int row = ty * 2 + rr;
            const float* rp = colbase + row * TS + (row & 12);   // skewed row base
            float4 q0 = *(const float4*)(rp + 0);
            float4 q1 = *(const float4*)(rp + 4);
            float4 q2 = *(const float4*)(rp + 8);
            float4 q3 = *(const float4*)(rp + 12);
            float4 q4 = *(const float4*)(rp + 16);
            float w[20];
            w[0]=q0.x;  w[1]=q0.y;  w[2]=q0.z;  w[3]=q0.w;
            w[4]=q1.x;  w[5]=q1.y;  w[6]=q1.z;  w[7]=q1.w;
            w[8]=q2.x;  w[9]=q2.y;  w[10]=q2.z; w[11]=q2.w;
            w[12]=q3.x; w[13]=q3.y; w[14]=q3.z; w[15]=q3.w;
            w[16]=q4.x; w[17]=q4.y; w[18]=q4.z; w[19]=q4.w;
            #pragma unroll
            for (int o = 0; o < 2; ++o) {
                if (rr - o >= 0 && rr - o < K) {           // compile-time fold
                    if ((need >> o) & 1) {
                        const int m = rc[rr - o];          // per-row column mask (SGPR)
                        const int s = (rr - o) & 1;
                        #pragma unroll
                        for (int j = 0; j < K; ++j) {
                            if ((m >> j) & 1) {            // scalar branch gates FMAs only
                                const float kv = kvs[s][j];
                                // plane col = 4tx+xx+j-5 -> window index xx+j+3
                                #pragma unroll
                                for (int xx = 0; xx < 4; ++xx)
                                    acc[o][xx] = fmaf(w[xx + j + 3], kv, acc[o][xx]);
                            }
                        }
                    }
                }
            }
        }
    }

    float* op = out + (size_t)bid * 4096 + (ty * 2) * 64 + tx * 4;
    #pragma unroll
    for (int o = 0; o < 2; ++o) {
        float4 v;
        v.x = acc[o][0]; v.y = acc[o][1]; v.z = acc[o][2]; v.w = acc[o][3];
        *(float4*)(op + o * 64) = v;
    }
}

extern "C" void kernel_launch(void* const* d_in, const int* in_sizes, int n_in,
                              void* d_out, int out_size, void* d_ws, size_t ws_size,
                              hipStream_t stream) {
    const float* x      = (const float*)d_in[0];
    const float* wcoord = (const float*)d_in[1];
    const float* radius = (const float*)d_in[2];
    const float* wts    = (const float*)d_in[3];
    float* out          = (float*)d_out;

    const int nplanes = 16 * PLANES;   // 6144 blocks, one 64x64 plane each
    smpconv_kernel<<<dim3(nplanes), dim3(512), 0, stream>>>(x, wcoord, radius, wts, out);
}